// Round 1
// baseline (1323.950 us; speedup 1.0000x reference)
//
#include <hip/hip_runtime.h>

#define BB 256
#define C0 64
#define LL 2048
#define PP 192
#define GG 48
#define CO 112

// ws layout (bytes):
//   [0, OUT1_BYTES)                       out1 as bf16   (201,326,592 B)
//   [OUT1_BYTES, +H_BYTES)                h as f32       (100,663,296 B)
//   zero-region zr (floats):
//     zr[0:64)      bn1 sum      zr[64:128)   bn1 sumsq
//     zr[128:320)   bn2 sum      zr[320:512)  bn2 sumsq
//     zr[512:12800) norms2 (256*48)
//     zr[12800:602624) sim (256*48*48)
//   params par (floats): [0:64) scale1 [64:128) shift1 [128:320) scale2 [320:512) shift2
static constexpr size_t OUT1_BYTES = (size_t)BB * PP * LL * 2;
static constexpr size_t H_BYTES    = (size_t)BB * GG * LL * 4;

__device__ __forceinline__ float bf2f(unsigned v) {
    union { unsigned u; float f; } a; a.u = v << 16; return a.f;
}
__device__ __forceinline__ float bf2f_hi(unsigned v) {
    union { unsigned u; float f; } a; a.u = v & 0xffff0000u; return a.f;
}
__device__ __forceinline__ unsigned short f2bf(float f) {
    union { float f; unsigned u; } a; a.f = f;
    unsigned u = a.u;
    u += 0x7fffu + ((u >> 16) & 1u);   // RNE; inputs are finite
    return (unsigned short)(u >> 16);
}

// K1: BN1 stats (sum, sumsq per channel) fused with copy of x into out[:, 0:64, :]
__global__ __launch_bounds__(256) void k1_bn1_stats_copy(
        const float* __restrict__ x, float* __restrict__ out,
        float* __restrict__ bn1sum, float* __restrict__ bn1sq) {
    int c = blockIdx.x, chunk = blockIdx.y, t = threadIdx.x;
    const float4* x4 = (const float4*)x;
    float4* o4 = (float4*)out;
    float s = 0.f, ss = 0.f;
    for (int j = 0; j < 32; ++j) {
        int idx = chunk * 8192 + j * 256 + t;      // float4 index within (b,l) space
        int b = idx >> 9, lq = idx & 511;
        float4 v = x4[(size_t)(b * C0 + c) * 512 + lq];
        s  += v.x + v.y + v.z + v.w;
        ss += v.x * v.x + v.y * v.y + v.z * v.z + v.w * v.w;
        o4[(size_t)(b * CO + c) * 512 + lq] = v;
    }
    __shared__ float rs[256], rq[256];
    rs[t] = s; rq[t] = ss;
    __syncthreads();
    for (int o = 128; o > 0; o >>= 1) {
        if (t < o) { rs[t] += rs[t + o]; rq[t] += rq[t + o]; }
        __syncthreads();
    }
    if (t == 0) { atomicAdd(&bn1sum[c], rs[0]); atomicAdd(&bn1sq[c], rq[0]); }
}

// finalize BN: scale = gamma*rsqrt(var+eps), shift = beta - mean*scale
__global__ void k_bn_final(const float* __restrict__ sums, const float* __restrict__ sqs,
                           const float* __restrict__ gamma, const float* __restrict__ beta,
                           float* __restrict__ scale, float* __restrict__ shift,
                           int C, float invN) {
    int c = threadIdx.x;
    if (c < C) {
        float mean = sums[c] * invN;
        float var  = sqs[c] * invN - mean * mean;
        float r    = rsqrtf(var + 1e-5f);
        float sc   = gamma[c] * r;
        scale[c] = sc;
        shift[c] = beta[c] - mean * sc;
    }
}

// K2: out1 = conv1x1(relu(bn1(x))), stored as bf16.
// Block: one b, 256 l's. Each wave owns 48 of 192 output planes (wave-uniform -> W1 via s_load).
__global__ __launch_bounds__(256) void k2_conv1(
        const float* __restrict__ x, const float* __restrict__ W1,
        const float* __restrict__ par, unsigned short* __restrict__ out1) {
    int b = blockIdx.x, lt = blockIdx.y, t = threadIdx.x;
    const float* scale1 = par;
    const float* shift1 = par + 64;
    __shared__ float yl[C0][256];
    int l0q = lt * 64;                                  // float4 units
    for (int j = 0; j < 16; ++j) {
        int f = j * 256 + t;                            // 0..4095 = 64c x 64 quads
        int c = f >> 6, lq = f & 63;
        float4 v = ((const float4*)x)[(size_t)(b * C0 + c) * 512 + l0q + lq];
        float sc = scale1[c], sh = shift1[c];
        float4 y;
        y.x = fmaxf(fmaf(sc, v.x, sh), 0.f);
        y.y = fmaxf(fmaf(sc, v.y, sh), 0.f);
        y.z = fmaxf(fmaf(sc, v.z, sh), 0.f);
        y.w = fmaxf(fmaf(sc, v.w, sh), 0.f);
        *(float4*)&yl[c][lq * 4] = y;
    }
    __syncthreads();
    int lane = t & 63;
    int wg = __builtin_amdgcn_readfirstlane(t >> 6);    // wave id 0..3, forced SGPR
    for (int ch = 0; ch < 6; ++ch) {
        float4 acc[8];
        #pragma unroll
        for (int i = 0; i < 8; ++i) acc[i] = make_float4(0.f, 0.f, 0.f, 0.f);
        for (int c = 0; c < C0; ++c) {
            float4 yv = *(const float4*)&yl[c][lane * 4];
            #pragma unroll
            for (int i = 0; i < 8; ++i) {
                float w = W1[(wg * 48 + ch * 8 + i) * C0 + c];   // uniform -> s_load
                acc[i].x = fmaf(w, yv.x, acc[i].x);
                acc[i].y = fmaf(w, yv.y, acc[i].y);
                acc[i].z = fmaf(w, yv.z, acc[i].z);
                acc[i].w = fmaf(w, yv.w, acc[i].w);
            }
        }
        #pragma unroll
        for (int i = 0; i < 8; ++i) {
            int p = wg * 48 + ch * 8 + i;
            ushort4 u;
            u.x = f2bf(acc[i].x); u.y = f2bf(acc[i].y);
            u.z = f2bf(acc[i].z); u.w = f2bf(acc[i].w);
            *(ushort4*)&out1[(size_t)(b * PP + p) * LL + lt * 256 + lane * 4] = u;
        }
    }
}

// K3: BN2 stats over out1 (bf16)
__global__ __launch_bounds__(256) void k3_bn2_stats(
        const unsigned short* __restrict__ out1,
        float* __restrict__ bn2sum, float* __restrict__ bn2sq) {
    int p = blockIdx.x, chunk = blockIdx.y, t = threadIdx.x;
    const ushort4* o4 = (const ushort4*)out1;
    float s = 0.f, ss = 0.f;
    for (int j = 0; j < 32; ++j) {
        int idx = chunk * 8192 + j * 256 + t;
        int b = idx >> 9, lq = idx & 511;
        ushort4 u = o4[(size_t)(b * PP + p) * 512 + lq];
        float v0 = bf2f(u.x), v1 = bf2f(u.y), v2 = bf2f(u.z), v3 = bf2f(u.w);
        s  += v0 + v1 + v2 + v3;
        ss += v0 * v0 + v1 * v1 + v2 * v2 + v3 * v3;
    }
    __shared__ float rs[256], rq[256];
    rs[t] = s; rq[t] = ss;
    __syncthreads();
    for (int o = 128; o > 0; o >>= 1) {
        if (t < o) { rs[t] += rs[t + o]; rq[t] += rq[t + o]; }
        __syncthreads();
    }
    if (t == 0) { atomicAdd(&bn2sum[p], rs[0]); atomicAdd(&bn2sq[p], rq[0]); }
}

// K4: h = conv3(relu(bn2(out1))) (pad=1) + per-(b,g) sum(h^2) partials.
// z tile (bf16, post-activation) staged in LDS: z[p][idx], idx = 3 + l_rel, halo at 2 / 131.
__global__ __launch_bounds__(256) void k4_conv2(
        const unsigned short* __restrict__ out1, const float* __restrict__ W2,
        const float* __restrict__ par, float* __restrict__ h,
        float* __restrict__ norms2) {
    int b = blockIdx.x, lt = blockIdx.y, t = threadIdx.x;
    const float* scale2 = par + 128;
    const float* shift2 = par + 320;
    __shared__ unsigned short zl[PP * 136];
    int l0 = lt * 128;
    const ushort4* o4 = (const ushort4*)out1;
    for (int j = 0; j < 24; ++j) {
        int f = j * 256 + t;                       // 0..6143 = 192p x 32 quads
        int p = f >> 5, lq = f & 31;
        ushort4 u = o4[(size_t)(b * PP + p) * 512 + lt * 32 + lq];
        float sc = scale2[p], sh = shift2[p];
        int base = p * 136 + 3 + lq * 4;
        zl[base + 0] = f2bf(fmaxf(fmaf(sc, bf2f(u.x), sh), 0.f));
        zl[base + 1] = f2bf(fmaxf(fmaf(sc, bf2f(u.y), sh), 0.f));
        zl[base + 2] = f2bf(fmaxf(fmaf(sc, bf2f(u.z), sh), 0.f));
        zl[base + 3] = f2bf(fmaxf(fmaf(sc, bf2f(u.w), sh), 0.f));
    }
    if (t < PP) {
        int p = t;
        float sc = scale2[p], sh = shift2[p];
        unsigned short lo = 0, hi = 0;
        if (l0 > 0)
            lo = f2bf(fmaxf(fmaf(sc, bf2f(out1[(size_t)(b * PP + p) * LL + l0 - 1]), sh), 0.f));
        if (l0 + 128 < LL)
            hi = f2bf(fmaxf(fmaf(sc, bf2f(out1[(size_t)(b * PP + p) * LL + l0 + 128]), sh), 0.f));
        zl[p * 136 + 2]   = lo;
        zl[p * 136 + 131] = hi;
    }
    __syncthreads();
    int lane = t & 63;
    int wg = __builtin_amdgcn_readfirstlane(t >> 6);   // wave id 0..3 -> g in [wg*12, wg*12+12)
    float acc[12][2];
    #pragma unroll
    for (int j = 0; j < 12; ++j) { acc[j][0] = 0.f; acc[j][1] = 0.f; }
    const unsigned* zu = (const unsigned*)zl;
    for (int p = 0; p < PP; ++p) {
        // lane handles l = 2*lane and 2*lane+1; taps are z_in[l-1..l+2] = ushorts (2+2lane .. 5+2lane)
        unsigned wa = zu[p * 68 + 1 + lane];
        unsigned wb = zu[p * 68 + 2 + lane];
        float z0 = bf2f(wa), z1 = bf2f_hi(wa);
        float z2 = bf2f(wb), z3 = bf2f_hi(wb);
        #pragma unroll
        for (int j = 0; j < 12; ++j) {
            const float* wr = &W2[((wg * 12 + j) * PP + p) * 3];   // uniform -> s_load
            float w0 = wr[0], w1 = wr[1], w2 = wr[2];
            acc[j][0] = fmaf(w0, z0, fmaf(w1, z1, fmaf(w2, z2, acc[j][0])));
            acc[j][1] = fmaf(w0, z1, fmaf(w1, z2, fmaf(w2, z3, acc[j][1])));
        }
    }
    #pragma unroll
    for (int j = 0; j < 12; ++j) {
        int g = wg * 12 + j;
        int l = l0 + 2 * lane;
        size_t off = (size_t)(b * GG + g) * LL + l;
        float2 hv; hv.x = acc[j][0]; hv.y = acc[j][1];
        *(float2*)&h[off] = hv;
        float nv = acc[j][0] * acc[j][0] + acc[j][1] * acc[j][1];
        for (int o = 32; o > 0; o >>= 1) nv += __shfl_down(nv, o);
        if (lane == 0) atomicAdd(&norms2[b * GG + g], nv);
    }
}

// K6: raw Gram sim[b,c,d] = sum_l h[b,c,l]*h[b,d,l], accumulated by atomics over 4 l-chunks.
__global__ __launch_bounds__(256) void k6_gram(
        const float* __restrict__ h, float* __restrict__ sim) {
    int b = blockIdx.x, ch = blockIdx.y, t = threadIdx.x;
    __shared__ float hl[GG * 260];                     // +4 pad vs 256 to break bank conflicts
    int tr = t >> 4, tc = t & 15;                      // 16x16 grid of 3x3 register tiles
    float s00 = 0, s01 = 0, s02 = 0, s10 = 0, s11 = 0, s12 = 0, s20 = 0, s21 = 0, s22 = 0;
    for (int sub = 0; sub < 2; ++sub) {
        __syncthreads();
        for (int j = 0; j < 12; ++j) {
            int f = j * 256 + t;                       // 48 rows x 64 quads
            int r = f >> 6, lq = f & 63;
            float4 v = ((const float4*)h)[(size_t)(b * GG + r) * 512 + ch * 128 + sub * 64 + lq];
            *(float4*)&hl[r * 260 + lq * 4] = v;
        }
        __syncthreads();
        for (int l4 = 0; l4 < 64; ++l4) {
            float4 r0 = *(const float4*)&hl[(3 * tr + 0) * 260 + l4 * 4];
            float4 r1 = *(const float4*)&hl[(3 * tr + 1) * 260 + l4 * 4];
            float4 r2 = *(const float4*)&hl[(3 * tr + 2) * 260 + l4 * 4];
            float4 c0 = *(const float4*)&hl[(3 * tc + 0) * 260 + l4 * 4];
            float4 c1 = *(const float4*)&hl[(3 * tc + 1) * 260 + l4 * 4];
            float4 c2 = *(const float4*)&hl[(3 * tc + 2) * 260 + l4 * 4];
            s00 += r0.x * c0.x + r0.y * c0.y + r0.z * c0.z + r0.w * c0.w;
            s01 += r0.x * c1.x + r0.y * c1.y + r0.z * c1.z + r0.w * c1.w;
            s02 += r0.x * c2.x + r0.y * c2.y + r0.z * c2.z + r0.w * c2.w;
            s10 += r1.x * c0.x + r1.y * c0.y + r1.z * c0.z + r1.w * c0.w;
            s11 += r1.x * c1.x + r1.y * c1.y + r1.z * c1.z + r1.w * c1.w;
            s12 += r1.x * c2.x + r1.y * c2.y + r1.z * c2.z + r1.w * c2.w;
            s20 += r2.x * c0.x + r2.y * c0.y + r2.z * c0.z + r2.w * c0.w;
            s21 += r2.x * c1.x + r2.y * c1.y + r2.z * c1.z + r2.w * c1.w;
            s22 += r2.x * c2.x + r2.y * c2.y + r2.z * c2.z + r2.w * c2.w;
        }
    }
    float* sb = &sim[(size_t)b * 2304];
    atomicAdd(&sb[(3 * tr + 0) * 48 + 3 * tc + 0], s00);
    atomicAdd(&sb[(3 * tr + 0) * 48 + 3 * tc + 1], s01);
    atomicAdd(&sb[(3 * tr + 0) * 48 + 3 * tc + 2], s02);
    atomicAdd(&sb[(3 * tr + 1) * 48 + 3 * tc + 0], s10);
    atomicAdd(&sb[(3 * tr + 1) * 48 + 3 * tc + 1], s11);
    atomicAdd(&sb[(3 * tr + 1) * 48 + 3 * tc + 2], s12);
    atomicAdd(&sb[(3 * tr + 2) * 48 + 3 * tc + 0], s20);
    atomicAdd(&sb[(3 * tr + 2) * 48 + 3 * tc + 1], s21);
    atomicAdd(&sb[(3 * tr + 2) * 48 + 3 * tc + 2], s22);
}

// K7: normalize sim by norms, softmax rows, fold residual into att diag, PV, write out[:,64:112,:]
__global__ __launch_bounds__(256) void k7_softmax_pv(
        const float* __restrict__ h, const float* __restrict__ sim,
        const float* __restrict__ norms2, float* __restrict__ out) {
    int b = blockIdx.x, ch = blockIdx.y, t = threadIdx.x;
    __shared__ float att[GG][GG];
    __shared__ float nrm[GG];
    if (t < GG) nrm[t] = sqrtf(norms2[b * GG + t]);
    __syncthreads();
    if (t < GG) {
        int r = t;
        const float* sr = &sim[(size_t)b * 2304 + r * 48];
        float nr = nrm[r];
        float m = -1e30f;
        for (int d = 0; d < GG; ++d) {
            float v = sr[d] / fmaxf(nr * nrm[d], 1e-8f);
            att[r][d] = v;
            m = fmaxf(m, v);
        }
        float ssum = 0.f;
        for (int d = 0; d < GG; ++d) {
            float e = __expf(att[r][d] - m);
            att[r][d] = e;
            ssum += e;
        }
        float inv = 1.f / ssum;
        for (int d = 0; d < GG; ++d) att[r][d] *= inv;
        att[r][r] += 1.0f;                      // residual: out = (att + I) @ h
    }
    __syncthreads();
    int l = ch * 512 + t;                       // this thread: l and l+256
    float h0[GG], h1[GG];
    #pragma unroll
    for (int d = 0; d < GG; ++d) {
        h0[d] = h[(size_t)(b * GG + d) * LL + l];
        h1[d] = h[(size_t)(b * GG + d) * LL + l + 256];
    }
    for (int c = 0; c < GG; ++c) {
        float a0 = 0.f, a1 = 0.f;
        #pragma unroll
        for (int dq = 0; dq < 12; ++dq) {
            float4 a4 = *(const float4*)&att[c][dq * 4];
            a0 += a4.x * h0[4 * dq] + a4.y * h0[4 * dq + 1] + a4.z * h0[4 * dq + 2] + a4.w * h0[4 * dq + 3];
            a1 += a4.x * h1[4 * dq] + a4.y * h1[4 * dq + 1] + a4.z * h1[4 * dq + 2] + a4.w * h1[4 * dq + 3];
        }
        out[(size_t)(b * CO + 64 + c) * LL + l] = a0;
        out[(size_t)(b * CO + 64 + c) * LL + l + 256] = a1;
    }
}

extern "C" void kernel_launch(void* const* d_in, const int* in_sizes, int n_in,
                              void* d_out, int out_size, void* d_ws, size_t ws_size,
                              hipStream_t stream) {
    const float* x      = (const float*)d_in[0];
    const float* gamma1 = (const float*)d_in[1];
    const float* beta1  = (const float*)d_in[2];
    const float* W1     = (const float*)d_in[3];
    const float* gamma2 = (const float*)d_in[4];
    const float* beta2  = (const float*)d_in[5];
    const float* W2     = (const float*)d_in[6];
    float* out = (float*)d_out;

    unsigned short* out1 = (unsigned short*)d_ws;                      // bf16
    float* h   = (float*)((char*)d_ws + OUT1_BYTES);
    float* zr  = (float*)((char*)d_ws + OUT1_BYTES + H_BYTES);
    float* par = zr + 602624;

    hipMemsetAsync(zr, 0, 602624 * sizeof(float), stream);

    const float invN = 1.0f / (float)((size_t)BB * LL);
    k1_bn1_stats_copy<<<dim3(64, 16), 256, 0, stream>>>(x, out, zr + 0, zr + 64);
    k_bn_final<<<1, 64, 0, stream>>>(zr + 0, zr + 64, gamma1, beta1, par + 0, par + 64, 64, invN);
    k2_conv1<<<dim3(BB, 8), 256, 0, stream>>>(x, W1, par, out1);
    k3_bn2_stats<<<dim3(PP, 16), 256, 0, stream>>>(out1, zr + 128, zr + 320);
    k_bn_final<<<1, 192, 0, stream>>>(zr + 128, zr + 320, gamma2, beta2, par + 128, par + 320, 192, invN);
    k4_conv2<<<dim3(BB, 16), 256, 0, stream>>>(out1, W2, par, h, zr + 512);
    k6_gram<<<dim3(BB, 4), 256, 0, stream>>>(h, zr + 12800);
    k7_softmax_pv<<<dim3(BB, 4), 256, 0, stream>>>(h, zr + 12800, zr + 512, out);
}

// Round 2
// 839.620 us; speedup vs baseline: 1.5768x; 1.5768x over previous
//
#include <hip/hip_runtime.h>

#define BB 256
#define C0 64
#define LL 2048
#define PP 192
#define GG 48
#define CO 112
#define PBK 24   // PP/8
#define CBK 8    // C0/8

typedef float f32x4 __attribute__((ext_vector_type(4)));
typedef __bf16 bf16x8 __attribute__((ext_vector_type(8)));

// ws layout:
//   [0, OUT1_BYTES)            out1 bf16 [b][pb][l][8]          201,326,592 B
//   [OUT1_BYTES, +H_BYTES)     h f32 [b][g][l]  (xT bf16 [b][cb][l][8] aliased here, dead after k2)
//   zr floats: [0:64) bn1sum [64:128) bn1sq [128:320) bn2sum [320:512) bn2sq
//              [512:12800) norms2  [12800:602624) sim
//   par floats: [0:64) scale1 [64:128) shift1 [128:320) scale2 [320:512) shift2
//   W1p bf16 [192][64]; W2p bf16 [3][48][192]
static constexpr size_t OUT1_BYTES = (size_t)BB * PP * LL * 2;
static constexpr size_t H_BYTES    = (size_t)BB * GG * LL * 4;
static constexpr int    ZR_FLOATS  = 602624;

__device__ __forceinline__ float bflo(unsigned w) { return __uint_as_float(w << 16); }
__device__ __forceinline__ float bfhi(unsigned w) { return __uint_as_float(w & 0xffff0000u); }
__device__ __forceinline__ unsigned pk2bf(float a, float b) {
    unsigned ua = __float_as_uint(a); ua += 0x7fffu + ((ua >> 16) & 1u);
    unsigned ub = __float_as_uint(b); ub += 0x7fffu + ((ub >> 16) & 1u);
    return (ua >> 16) | (ub & 0xffff0000u);
}
__device__ __forceinline__ unsigned short f2bf(float f) {
    unsigned u = __float_as_uint(f); u += 0x7fffu + ((u >> 16) & 1u);
    return (unsigned short)(u >> 16);
}
__device__ __forceinline__ unsigned act2(unsigned w, float s0, float s1, float h0, float h1) {
    float y0 = fmaxf(fmaf(s0, bflo(w), h0), 0.f);
    float y1 = fmaxf(fmaf(s1, bfhi(w), h1), 0.f);
    return pk2bf(y0, y1);
}

// pack W1 -> bf16 [192][64]; W2 [48][192][3] -> bf16 [tap][48][192]
__global__ void kp_pack(const float* __restrict__ W1, const float* __restrict__ W2,
                        unsigned short* __restrict__ W1p, unsigned short* __restrict__ W2p) {
    int i = blockIdx.x * 256 + threadIdx.x;
    if (i < PP * C0) W1p[i] = f2bf(W1[i]);
    if (i < 3 * GG * PP) {
        int tap = i / (GG * PP), r = i % (GG * PP);
        int g = r / PP, p = r % PP;
        W2p[i] = f2bf(W2[(g * PP + p) * 3 + tap]);
    }
}

// K1: BN1 stats + copy x -> out[:,0:64,:] + write xT bf16 [b][cb][l][8]
__global__ __launch_bounds__(256) void k1_stats_copy_xT(
        const float* __restrict__ x, float* __restrict__ out, unsigned short* __restrict__ xT,
        float* __restrict__ bn1sum, float* __restrict__ bn1sq) {
    int b = blockIdx.x, lc = blockIdx.y, t = threadIdx.x;
    int c = t >> 2, li = t & 3;
    float s = 0.f, ss = 0.f;
    for (int q = 0; q < 16; ++q) {
        int l = lc * 256 + li * 64 + q * 4;
        float4 v = *(const float4*)&x[(size_t)(b * C0 + c) * LL + l];
        *(float4*)&out[(size_t)(b * CO + c) * LL + l] = v;
        s += v.x + v.y + v.z + v.w;
        ss += v.x * v.x + v.y * v.y + v.z * v.z + v.w * v.w;
        unsigned short* xp = &xT[(((size_t)(b * CBK + (c >> 3))) * LL + l) * 8 + (c & 7)];
        xp[0] = f2bf(v.x); xp[8] = f2bf(v.y); xp[16] = f2bf(v.z); xp[24] = f2bf(v.w);
    }
    s += __shfl_xor(s, 1); s += __shfl_xor(s, 2);
    ss += __shfl_xor(ss, 1); ss += __shfl_xor(ss, 2);
    if (li == 0) { atomicAdd(&bn1sum[c], s); atomicAdd(&bn1sq[c], ss); }
}

__global__ void k_bn_final(const float* __restrict__ sums, const float* __restrict__ sqs,
                           const float* __restrict__ gamma, const float* __restrict__ beta,
                           float* __restrict__ scale, float* __restrict__ shift,
                           int C, float invN) {
    int c = threadIdx.x;
    if (c < C) {
        float mean = sums[c] * invN;
        float var  = sqs[c] * invN - mean * mean;
        float r    = rsqrtf(var + 1e-5f);
        float sc   = gamma[c] * r;
        scale[c] = sc;
        shift[c] = beta[c] - mean * sc;
    }
}

// K2: out1 = conv1x1(relu(bn1(x))) via MFMA. A=W1p (g x c), B=activated xT (c x l).
__global__ __launch_bounds__(256, 2) void k2_conv1(
        const unsigned short* __restrict__ xT, const unsigned short* __restrict__ W1p,
        const float* __restrict__ par, unsigned short* __restrict__ out1) {
    int b = blockIdx.x, lt = blockIdx.y, t = threadIdx.x;
    int w = __builtin_amdgcn_readfirstlane(t >> 6);
    int lane = t & 63, lm = lane & 15, lg = lane >> 4;
    union AF { uint4 q; bf16x8 v; };
    AF afr[3][2];
    #pragma unroll
    for (int gf = 0; gf < 3; ++gf)
        #pragma unroll
        for (int kc = 0; kc < 2; ++kc)
            afr[gf][kc].q = *(const uint4*)&W1p[(w * 48 + gf * 16 + lm) * C0 + kc * 32 + lg * 8];
    f32x4 acc[3][8];
    #pragma unroll
    for (int gf = 0; gf < 3; ++gf)
        #pragma unroll
        for (int lf = 0; lf < 8; ++lf) acc[gf][lf] = f32x4{0.f, 0.f, 0.f, 0.f};
    int l0 = lt * 128;
    size_t xbase = (size_t)b * CBK * LL * 8;
    #pragma unroll
    for (int kc = 0; kc < 2; ++kc) {
        int cb = kc * 4 + lg;
        float4 sca = *(const float4*)&par[8 * cb];
        float4 scb = *(const float4*)&par[8 * cb + 4];
        float4 sha = *(const float4*)&par[64 + 8 * cb];
        float4 shb = *(const float4*)&par[64 + 8 * cb + 4];
        #pragma unroll
        for (int lf = 0; lf < 8; ++lf) {
            int l = l0 + lf * 16 + lm;
            uint4 q = *(const uint4*)&xT[xbase + ((size_t)cb * LL + l) * 8];
            union { uint4 q; bf16x8 v; } bf;
            bf.q.x = act2(q.x, sca.x, sca.y, sha.x, sha.y);
            bf.q.y = act2(q.y, sca.z, sca.w, sha.z, sha.w);
            bf.q.z = act2(q.z, scb.x, scb.y, shb.x, shb.y);
            bf.q.w = act2(q.w, scb.z, scb.w, shb.z, shb.w);
            #pragma unroll
            for (int gf = 0; gf < 3; ++gf)
                acc[gf][lf] = __builtin_amdgcn_mfma_f32_16x16x32_bf16(afr[gf][kc].v, bf.v, acc[gf][lf], 0, 0, 0);
        }
    }
    #pragma unroll
    for (int gf = 0; gf < 3; ++gf) {
        int g0 = w * 48 + gf * 16 + lg * 4;
        size_t obase = ((size_t)b * PBK + (g0 >> 3)) * LL * 8 + (g0 & 7);
        #pragma unroll
        for (int lf = 0; lf < 8; ++lf) {
            int l = l0 + lf * 16 + lm;
            uint2 pk;
            pk.x = pk2bf(acc[gf][lf][0], acc[gf][lf][1]);
            pk.y = pk2bf(acc[gf][lf][2], acc[gf][lf][3]);
            *(uint2*)&out1[obase + (size_t)l * 8] = pk;
        }
    }
}

// K3: BN2 stats over out1 [b][pb][l][8]
__global__ __launch_bounds__(256) void k3_bn2_stats(
        const unsigned short* __restrict__ out1,
        float* __restrict__ bn2sum, float* __restrict__ bn2sq) {
    int pb = blockIdx.x, chunk = blockIdx.y, t = threadIdx.x;
    float s[8], ss[8];
    #pragma unroll
    for (int j = 0; j < 8; ++j) { s[j] = 0.f; ss[j] = 0.f; }
    for (int i = 0; i < 64; ++i) {
        int idx = chunk * 16384 + i * 256 + t;
        int b = idx >> 11, l = idx & 2047;
        uint4 q = *(const uint4*)&out1[(((size_t)(b * PBK + pb)) * LL + l) * 8];
        unsigned uu[4] = {q.x, q.y, q.z, q.w};
        #pragma unroll
        for (int j = 0; j < 4; ++j) {
            float f0 = bflo(uu[j]), f1 = bfhi(uu[j]);
            s[2 * j] += f0;      ss[2 * j] += f0 * f0;
            s[2 * j + 1] += f1;  ss[2 * j + 1] += f1 * f1;
        }
    }
    #pragma unroll
    for (int m = 1; m < 64; m <<= 1)
        #pragma unroll
        for (int j = 0; j < 8; ++j) { s[j] += __shfl_xor(s[j], m); ss[j] += __shfl_xor(ss[j], m); }
    if ((t & 63) == 0)
        #pragma unroll
        for (int j = 0; j < 8; ++j) {
            atomicAdd(&bn2sum[pb * 8 + j], s[j]);
            atomicAdd(&bn2sq[pb * 8 + j], ss[j]);
        }
}

// K4: h = conv3(relu(bn2(out1))) via MFMA. A=W2p[tap] (g x p), B=activated out1 (p x l).
__global__ __launch_bounds__(256, 2) void k4_conv2(
        const unsigned short* __restrict__ out1, const unsigned short* __restrict__ W2p,
        const float* __restrict__ par, float* __restrict__ h, float* __restrict__ norms2) {
    int b = blockIdx.x, lt = blockIdx.y, t = threadIdx.x;
    int w = __builtin_amdgcn_readfirstlane(t >> 6);
    int lane = t & 63, lm = lane & 15, lg = lane >> 4;
    int lb = lt * 128 + w * 32;
    f32x4 acc[3][2];
    #pragma unroll
    for (int gf = 0; gf < 3; ++gf) { acc[gf][0] = f32x4{0.f,0.f,0.f,0.f}; acc[gf][1] = f32x4{0.f,0.f,0.f,0.f}; }
    size_t obase = (size_t)b * PBK * LL * 8;
    for (int pc = 0; pc < 6; ++pc) {
        int pb = pc * 4 + lg;
        float4 sca = *(const float4*)&par[128 + 8 * pb];
        float4 scb = *(const float4*)&par[128 + 8 * pb + 4];
        float4 sha = *(const float4*)&par[320 + 8 * pb];
        float4 shb = *(const float4*)&par[320 + 8 * pb + 4];
        #pragma unroll
        for (int tap = 0; tap < 3; ++tap) {
            union AF { uint4 q; bf16x8 v; };
            AF afr[3];
            #pragma unroll
            for (int gf = 0; gf < 3; ++gf)
                afr[gf].q = *(const uint4*)&W2p[(tap * GG + gf * 16 + lm) * PP + pc * 32 + lg * 8];
            #pragma unroll
            for (int lf = 0; lf < 2; ++lf) {
                int lz = lb + lf * 16 + lm + tap - 1;
                union { uint4 q; bf16x8 v; } bf;
                if ((unsigned)lz < (unsigned)LL) {
                    uint4 q = *(const uint4*)&out1[obase + ((size_t)pb * LL + lz) * 8];
                    bf.q.x = act2(q.x, sca.x, sca.y, sha.x, sha.y);
                    bf.q.y = act2(q.y, sca.z, sca.w, sha.z, sha.w);
                    bf.q.z = act2(q.z, scb.x, scb.y, shb.x, shb.y);
                    bf.q.w = act2(q.w, scb.z, scb.w, shb.z, shb.w);
                } else {
                    bf.q = uint4{0u, 0u, 0u, 0u};
                }
                #pragma unroll
                for (int gf = 0; gf < 3; ++gf)
                    acc[gf][lf] = __builtin_amdgcn_mfma_f32_16x16x32_bf16(afr[gf].v, bf.v, acc[gf][lf], 0, 0, 0);
            }
        }
    }
    #pragma unroll
    for (int gf = 0; gf < 3; ++gf) {
        #pragma unroll
        for (int lf = 0; lf < 2; ++lf) {
            int l = lb + lf * 16 + lm;
            #pragma unroll
            for (int r = 0; r < 4; ++r) {
                int g = gf * 16 + lg * 4 + r;
                h[((size_t)(b * GG + g)) * LL + l] = acc[gf][lf][r];
            }
        }
        #pragma unroll
        for (int r = 0; r < 4; ++r) {
            float nv = acc[gf][0][r] * acc[gf][0][r] + acc[gf][1][r] * acc[gf][1][r];
            nv += __shfl_xor(nv, 1); nv += __shfl_xor(nv, 2);
            nv += __shfl_xor(nv, 4); nv += __shfl_xor(nv, 8);
            if (lm == 0) atomicAdd(&norms2[b * GG + gf * 16 + lg * 4 + r], nv);
        }
    }
}

// K6: raw Gram sim[b,c,d] = sum_l h[b,c,l]*h[b,d,l]
__global__ __launch_bounds__(256) void k6_gram(
        const float* __restrict__ h, float* __restrict__ sim) {
    int b = blockIdx.x, ch = blockIdx.y, t = threadIdx.x;
    __shared__ float hl[GG * 260];
    int tr = t >> 4, tc = t & 15;
    float s00 = 0, s01 = 0, s02 = 0, s10 = 0, s11 = 0, s12 = 0, s20 = 0, s21 = 0, s22 = 0;
    for (int sub = 0; sub < 2; ++sub) {
        __syncthreads();
        for (int j = 0; j < 12; ++j) {
            int f = j * 256 + t;
            int r = f >> 6, lq = f & 63;
            float4 v = ((const float4*)h)[(size_t)(b * GG + r) * 512 + ch * 128 + sub * 64 + lq];
            *(float4*)&hl[r * 260 + lq * 4] = v;
        }
        __syncthreads();
        for (int l4 = 0; l4 < 64; ++l4) {
            float4 r0 = *(const float4*)&hl[(3 * tr + 0) * 260 + l4 * 4];
            float4 r1 = *(const float4*)&hl[(3 * tr + 1) * 260 + l4 * 4];
            float4 r2 = *(const float4*)&hl[(3 * tr + 2) * 260 + l4 * 4];
            float4 c0 = *(const float4*)&hl[(3 * tc + 0) * 260 + l4 * 4];
            float4 c1 = *(const float4*)&hl[(3 * tc + 1) * 260 + l4 * 4];
            float4 c2 = *(const float4*)&hl[(3 * tc + 2) * 260 + l4 * 4];
            s00 += r0.x * c0.x + r0.y * c0.y + r0.z * c0.z + r0.w * c0.w;
            s01 += r0.x * c1.x + r0.y * c1.y + r0.z * c1.z + r0.w * c1.w;
            s02 += r0.x * c2.x + r0.y * c2.y + r0.z * c2.z + r0.w * c2.w;
            s10 += r1.x * c0.x + r1.y * c0.y + r1.z * c0.z + r1.w * c0.w;
            s11 += r1.x * c1.x + r1.y * c1.y + r1.z * c1.z + r1.w * c1.w;
            s12 += r1.x * c2.x + r1.y * c2.y + r1.z * c2.z + r1.w * c2.w;
            s20 += r2.x * c0.x + r2.y * c0.y + r2.z * c0.z + r2.w * c0.w;
            s21 += r2.x * c1.x + r2.y * c1.y + r2.z * c1.z + r2.w * c1.w;
            s22 += r2.x * c2.x + r2.y * c2.y + r2.z * c2.z + r2.w * c2.w;
        }
    }
    float* sb = &sim[(size_t)b * 2304];
    atomicAdd(&sb[(3 * tr + 0) * 48 + 3 * tc + 0], s00);
    atomicAdd(&sb[(3 * tr + 0) * 48 + 3 * tc + 1], s01);
    atomicAdd(&sb[(3 * tr + 0) * 48 + 3 * tc + 2], s02);
    atomicAdd(&sb[(3 * tr + 1) * 48 + 3 * tc + 0], s10);
    atomicAdd(&sb[(3 * tr + 1) * 48 + 3 * tc + 1], s11);
    atomicAdd(&sb[(3 * tr + 1) * 48 + 3 * tc + 2], s12);
    atomicAdd(&sb[(3 * tr + 2) * 48 + 3 * tc + 0], s20);
    atomicAdd(&sb[(3 * tr + 2) * 48 + 3 * tc + 1], s21);
    atomicAdd(&sb[(3 * tr + 2) * 48 + 3 * tc + 2], s22);
}

// K7: cosine-normalize, softmax, residual, PV -> out[:,64:112,:]
__global__ __launch_bounds__(256) void k7_softmax_pv(
        const float* __restrict__ h, const float* __restrict__ sim,
        const float* __restrict__ norms2, float* __restrict__ out) {
    int b = blockIdx.x, ch = blockIdx.y, t = threadIdx.x;
    __shared__ float att[GG][GG];
    __shared__ float nrm[GG];
    if (t < GG) nrm[t] = sqrtf(norms2[b * GG + t]);
    __syncthreads();
    if (t < GG) {
        int r = t;
        const float* sr = &sim[(size_t)b * 2304 + r * 48];
        float nr = nrm[r];
        float m = -1e30f;
        for (int d = 0; d < GG; ++d) {
            float v = sr[d] / fmaxf(nr * nrm[d], 1e-8f);
            att[r][d] = v;
            m = fmaxf(m, v);
        }
        float ssum = 0.f;
        for (int d = 0; d < GG; ++d) {
            float e = __expf(att[r][d] - m);
            att[r][d] = e;
            ssum += e;
        }
        float inv = 1.f / ssum;
        for (int d = 0; d < GG; ++d) att[r][d] *= inv;
        att[r][r] += 1.0f;
    }
    __syncthreads();
    int l = ch * 512 + t;
    float h0[GG], h1[GG];
    #pragma unroll
    for (int d = 0; d < GG; ++d) {
        h0[d] = h[(size_t)(b * GG + d) * LL + l];
        h1[d] = h[(size_t)(b * GG + d) * LL + l + 256];
    }
    for (int c = 0; c < GG; ++c) {
        float a0 = 0.f, a1 = 0.f;
        #pragma unroll
        for (int dq = 0; dq < 12; ++dq) {
            float4 a4 = *(const float4*)&att[c][dq * 4];
            a0 += a4.x * h0[4 * dq] + a4.y * h0[4 * dq + 1] + a4.z * h0[4 * dq + 2] + a4.w * h0[4 * dq + 3];
            a1 += a4.x * h1[4 * dq] + a4.y * h1[4 * dq + 1] + a4.z * h1[4 * dq + 2] + a4.w * h1[4 * dq + 3];
        }
        out[(size_t)(b * CO + 64 + c) * LL + l] = a0;
        out[(size_t)(b * CO + 64 + c) * LL + l + 256] = a1;
    }
}

extern "C" void kernel_launch(void* const* d_in, const int* in_sizes, int n_in,
                              void* d_out, int out_size, void* d_ws, size_t ws_size,
                              hipStream_t stream) {
    const float* x      = (const float*)d_in[0];
    const float* gamma1 = (const float*)d_in[1];
    const float* beta1  = (const float*)d_in[2];
    const float* W1     = (const float*)d_in[3];
    const float* gamma2 = (const float*)d_in[4];
    const float* beta2  = (const float*)d_in[5];
    const float* W2     = (const float*)d_in[6];
    float* out = (float*)d_out;

    unsigned short* out1 = (unsigned short*)d_ws;
    float* h = (float*)((char*)d_ws + OUT1_BYTES);
    unsigned short* xT = (unsigned short*)h;                 // aliased; dead after k2
    float* zr  = (float*)((char*)d_ws + OUT1_BYTES + H_BYTES);
    float* par = zr + ZR_FLOATS;
    unsigned short* W1p = (unsigned short*)(par + 512);
    unsigned short* W2p = W1p + PP * C0;

    hipMemsetAsync(zr, 0, (size_t)ZR_FLOATS * sizeof(float), stream);

    const float invN = 1.0f / (float)((size_t)BB * LL);
    kp_pack<<<108, 256, 0, stream>>>(W1, W2, W1p, W2p);
    k1_stats_copy_xT<<<dim3(BB, 8), 256, 0, stream>>>(x, out, xT, zr + 0, zr + 64);
    k_bn_final<<<1, 64, 0, stream>>>(zr + 0, zr + 64, gamma1, beta1, par + 0, par + 64, 64, invN);
    k2_conv1<<<dim3(BB, 16), 256, 0, stream>>>(xT, W1p, par, out1);
    k3_bn2_stats<<<dim3(PBK, 32), 256, 0, stream>>>(out1, zr + 128, zr + 320);
    k_bn_final<<<1, 192, 0, stream>>>(zr + 128, zr + 320, gamma2, beta2, par + 128, par + 320, 192, invN);
    k4_conv2<<<dim3(BB, 16), 256, 0, stream>>>(out1, W2p, par, h, zr + 512);
    k6_gram<<<dim3(BB, 4), 256, 0, stream>>>(h, zr + 12800);
    k7_softmax_pv<<<dim3(BB, 4), 256, 0, stream>>>(h, zr + 12800, zr + 512, out);
}